// Round 2
// baseline (446.978 us; speedup 1.0000x reference)
//
#include <hip/hip_runtime.h>
#include <hip/hip_bf16.h>

// FISSA forward, MI355X. One workgroup per batch element (B=1024), 512 threads
// (8 waves). All intermediates fp32 in LDS. Shapes: L=50, D=64, S=2 layers.
// All float tensors are fp32 (per reference setup_inputs); output fp32.
// LDS: 4 big 50x65 buffers + 50x52 scores + small params = 64,200 B (<64 KiB).

#define NB 1024
#define LL 50
#define DD 64
#define LD 65   // padded row stride for 50x64 buffers (breaks 64-stride bank conflicts)
#define LDC 52  // padded row stride for 50x50 score/c1/c2 buffer
#define NEGV (-4294967295.0f)

__device__ __forceinline__ float wsum(float v) {
#pragma unroll
  for (int m = 32; m >= 1; m >>= 1) v += __shfl_xor(v, m, 64);
  return v;
}
__device__ __forceinline__ float wmax(float v) {
#pragma unroll
  for (int m = 32; m >= 1; m >>= 1) v = fmaxf(v, __shfl_xor(v, m, 64));
  return v;
}

__global__ __launch_bounds__(512, 1) void fissa_kernel(
    const int* __restrict__ user_items, const int* __restrict__ pos_items,
    const int* __restrict__ neg_items, const float* __restrict__ pmask,
    const float* __restrict__ item_emb, const float* __restrict__ pos_emb,
    const float* __restrict__ Qs, const float* __restrict__ Ks,
    const float* __restrict__ Vs, const float* __restrict__ c1w,
    const float* __restrict__ c1b, const float* __restrict__ c2w,
    const float* __restrict__ c2b, const float* __restrict__ query,
    const float* __restrict__ Klba, const float* __restrict__ Vlba,
    const float* __restrict__ l1w, const float* __restrict__ l1b,
    const float* __restrict__ l2w, const float* __restrict__ l2b,
    const float* __restrict__ gw, const float* __restrict__ gb,
    float* __restrict__ out) {
  __shared__ float s_in[LL * LD];  // LN'd inputs (kept for LBA branch)
  __shared__ float s_x[LL * LD];   // current x / att / ff (in-place residuals)
  __shared__ float s_a[LL * LD];   // Qx -> Vx -> Kx_lba
  __shared__ float s_b[LL * LD];   // Kx -> h  -> Vx_lba
  __shared__ float s_c[LL * LDC];  // scores -> c1 -> c2
  __shared__ float s_mask[64], s_bias[64], s_qv[64], s_glo[64], s_gw[192], s_scal[2];

  const int b = blockIdx.x;
  const int tid = threadIdx.x;
  const int wv = tid >> 6, ln = tid & 63;

  // ---- stage small params + embedding gather + pos-emb + mask ----
  if (tid < 64) s_mask[tid] = (tid < LL) ? pmask[b * LL + tid] : 0.f;
  else if (tid < 128) s_qv[tid - 64] = query[tid - 64];
  else if (tid < 320) s_gw[tid - 128] = gw[tid - 128];

  for (int idx = tid; idx < LL * DD; idx += 512) {
    int l = idx >> 6, d = idx & 63;
    int u = user_items[b * LL + l];
    float mk = pmask[b * LL + l];
    s_in[l * LD + d] = (item_emb[u * DD + d] + pos_emb[idx]) * mk;
  }
  __syncthreads();
  // LN rows of s_in; copy to s_x
  for (int r = wv; r < LL; r += 8) {
    float v = s_in[r * LD + ln];
    float m = wsum(v) * (1.f / 64.f);
    float df = v - m;
    float var = wsum(df * df) * (1.f / 64.f);
    float o = df / sqrtf(var + 1e-8f);
    s_in[r * LD + ln] = o;
    s_x[r * LD + ln] = o;
  }
  __syncthreads();

  // ---- SAB layers ----
  for (int i = 0; i < 2; ++i) {
    const float* Qw = Qs + i * DD * DD;
    const float* Kw = Ks + i * DD * DD;
    const float* Vw = Vs + i * DD * DD;
    // Qx -> s_a, Kx -> s_b
    for (int idx = tid; idx < LL * DD; idx += 512) {
      int q = idx >> 6, j = idx & 63;
      const float* xr = &s_x[q * LD];
      float aq = 0.f, ak = 0.f;
#pragma unroll 8
      for (int k = 0; k < DD; ++k) {
        float xv = xr[k];
        aq += xv * Qw[k * DD + j];
        ak += xv * Kw[k * DD + j];
      }
      s_a[q * LD + j] = aq;
      s_b[q * LD + j] = ak;
    }
    __syncthreads();
    // scores -> s_c (raw masked scores, NO softmax, per reference)
    for (int idx = tid; idx < LL * LL; idx += 512) {
      int q = idx / LL, k = idx - q * LL;
      const float* qr = &s_a[q * LD];
      const float* kr = &s_b[k * LD];
      float acc = 0.f;
#pragma unroll
      for (int d = 0; d < DD; ++d) acc += qr[d] * kr[d];
      float sc = acc * 0.125f;              // / sqrt(64)
      if (k > q) sc = NEGV;                 // causal
      if (s_mask[k] == 0.f) sc = NEGV;      // key mask
      sc *= s_mask[q];                      // * padding_mask (broadcast over k)
      s_c[q * LDC + k] = sc;
    }
    __syncthreads();
    // Vx -> s_a (Qx dead)
    for (int idx = tid; idx < LL * DD; idx += 512) {
      int q = idx >> 6, j = idx & 63;
      const float* xr = &s_x[q * LD];
      float av = 0.f;
#pragma unroll 8
      for (int k = 0; k < DD; ++k) av += xr[k] * Vw[k * DD + j];
      s_a[q * LD + j] = av;
    }
    __syncthreads();
    // att = scores@Vx + x, in place into s_x (each thread touches only its own elem)
    for (int idx = tid; idx < LL * DD; idx += 512) {
      int q = idx >> 6, d = idx & 63;
      float acc = s_x[q * LD + d];
#pragma unroll
      for (int k = 0; k < LL; ++k) acc += s_c[q * LDC + k] * s_a[k * LD + d];
      s_x[q * LD + d] = acc;
    }
    __syncthreads();
    for (int r = wv; r < LL; r += 8) {  // LN(att)
      float v = s_x[r * LD + ln];
      float m = wsum(v) * (1.f / 64.f);
      float df = v - m;
      float var = wsum(df * df) * (1.f / 64.f);
      s_x[r * LD + ln] = df / sqrtf(var + 1e-8f);
    }
    __syncthreads();
    // stage c1 -> s_c, c1b -> s_bias
    for (int e = tid; e < LL * LL; e += 512) {
      int q = e / LL;
      s_c[q * LDC + (e - q * LL)] = c1w[i * LL * LL + e];
    }
    if (tid < LL) s_bias[tid] = c1b[i * LL + tid];
    __syncthreads();
    // h = relu(c1 @ att + c1b) -> s_b (Kx dead)
    for (int idx = tid; idx < LL * DD; idx += 512) {
      int q = idx >> 6, d = idx & 63;
      float acc = s_bias[q];
#pragma unroll
      for (int j = 0; j < LL; ++j) acc += s_c[q * LDC + j] * s_x[j * LD + d];
      s_b[q * LD + d] = fmaxf(acc, 0.f);
    }
    __syncthreads();
    // stage c2 -> s_c, c2b -> s_bias
    for (int e = tid; e < LL * LL; e += 512) {
      int q = e / LL;
      s_c[q * LDC + (e - q * LL)] = c2w[i * LL * LL + e];
    }
    if (tid < LL) s_bias[tid] = c2b[i * LL + tid];
    __syncthreads();
    // ff = c2 @ h + c2b + att, *mask, in place into s_x; then LN -> next x
    for (int idx = tid; idx < LL * DD; idx += 512) {
      int q = idx >> 6, d = idx & 63;
      float acc = s_bias[q] + s_x[q * LD + d];
#pragma unroll
      for (int j = 0; j < LL; ++j) acc += s_c[q * LDC + j] * s_b[j * LD + d];
      s_x[q * LD + d] = acc * s_mask[q];
    }
    __syncthreads();
    for (int r = wv; r < LL; r += 8) {
      float v = s_x[r * LD + ln];
      float m = wsum(v) * (1.f / 64.f);
      float df = v - m;
      float var = wsum(df * df) * (1.f / 64.f);
      s_x[r * LD + ln] = df / sqrtf(var + 1e-8f);
    }
    __syncthreads();
  }

  // ---- LBA (global) branch: Kx -> s_a, Vx -> s_b from s_in ----
  for (int idx = tid; idx < LL * DD; idx += 512) {
    int q = idx >> 6, j = idx & 63;
    const float* xr = &s_in[q * LD];
    float ak = 0.f, av = 0.f;
#pragma unroll 8
    for (int k = 0; k < DD; ++k) {
      float xv = xr[k];
      ak += xv * Klba[k * DD + j];
      av += xv * Vlba[k * DD + j];
    }
    s_a[q * LD + j] = ak;
    s_b[q * LD + j] = av;
  }
  __syncthreads();
  if (wv == 0) {  // single-wave mini-stage (no barriers inside)
    float sc = -INFINITY;
    if (ln < LL) {
      float acc = 0.f;
#pragma unroll
      for (int d = 0; d < DD; ++d) acc += s_qv[d] * s_a[ln * LD + d];
      sc = acc;
      if (s_mask[ln] == 0.f) sc = NEGV;
    }
    float mx = wmax(sc);
    float e = (ln < LL) ? expf(sc - mx) : 0.f;
    float den = wsum(e);
    if (ln < LL) s_bias[ln] = e / den;  // softmax probs (intra-wave RAW, compiler waits)
    float acc = 0.f;
#pragma unroll
    for (int l = 0; l < LL; ++l) acc += s_bias[l] * s_b[l * LD + ln];
    float m = wsum(acc) * (1.f / 64.f);
    float df = acc - m;
    float var = wsum(df * df) * (1.f / 64.f);
    float g = df / sqrtf(var + 1e-8f);  // LN(glo)
    float w1 = l1w[0], bb1 = l1b[0], w2 = l2w[0], bb2 = l2b[0];
    float h = fmaxf(w1 * g + bb1, 0.f);
    float g2 = w2 * h + bb2 + g;
    m = wsum(g2) * (1.f / 64.f);
    df = g2 - m;
    var = wsum(df * df) * (1.f / 64.f);
    float glo = df / sqrtf(var + 1e-8f);  // final glo
    s_glo[ln] = glo;
    float gs = wsum(glo * s_gw[64 + ln]);  // glo part of the gating logit
    if (ln == 0) s_scal[0] = gs + gb[0];
  }
  __syncthreads();

  // ---- gating + output: one wave per (pos/neg, l) row ----
  float g2c = s_scal[0];
  for (int row = wv; row < 2 * LL; row += 8) {
    int sgn = row >= LL;
    int l = row - sgn * LL;
    int u = user_items[b * LL + l];
    int it = sgn ? neg_items[b * LL + l] : pos_items[b * LL + l];
    float ie_d = item_emb[u * DD + ln];
    float mi_d = item_emb[it * DD + ln];
    float logit = wsum(ie_d * s_gw[ln] + mi_d * s_gw[128 + ln]) + g2c;
    float sg = 1.f / (1.f + expf(-logit));
    float g = 1.f / (1.f + expf(-sg));  // sigmoid(sigmoid(logit))
    float od = (s_x[l * LD + ln] * g + s_glo[ln] * (1.f - g)) * s_mask[l];
    float m = wsum(od) * (1.f / 64.f);
    float df = od - m;
    float var = wsum(df * df) * (1.f / 64.f);
    float o = df / sqrtf(var + 1e-8f);
    float res = wsum(o * mi_d);
    if (ln == 0) out[(sgn * NB + b) * LL + l] = res;
  }
}

extern "C" void kernel_launch(void* const* d_in, const int* in_sizes, int n_in,
                              void* d_out, int out_size, void* d_ws, size_t ws_size,
                              hipStream_t stream) {
  const int* user_items = (const int*)d_in[0];
  const int* pos_items = (const int*)d_in[1];
  const int* neg_items = (const int*)d_in[2];
  const float* pmask = (const float*)d_in[3];
  const float* item_emb = (const float*)d_in[4];
  const float* pos_emb = (const float*)d_in[5];
  const float* Qs = (const float*)d_in[6];
  const float* Ks = (const float*)d_in[7];
  const float* Vs = (const float*)d_in[8];
  const float* c1w = (const float*)d_in[9];
  const float* c1b = (const float*)d_in[10];
  const float* c2w = (const float*)d_in[11];
  const float* c2b = (const float*)d_in[12];
  const float* query = (const float*)d_in[13];
  const float* Klba = (const float*)d_in[14];
  const float* Vlba = (const float*)d_in[15];
  const float* l1w = (const float*)d_in[16];
  const float* l1b = (const float*)d_in[17];
  const float* l2w = (const float*)d_in[18];
  const float* l2b = (const float*)d_in[19];
  const float* gw = (const float*)d_in[20];
  const float* gb = (const float*)d_in[21];
  float* out = (float*)d_out;

  fissa_kernel<<<dim3(NB), dim3(512), 0, stream>>>(
      user_items, pos_items, neg_items, pmask, item_emb, pos_emb, Qs, Ks, Vs,
      c1w, c1b, c2w, c2b, query, Klba, Vlba, l1w, l1b, l2w, l2b, gw, gb, out);
}

// Round 3
// 402.079 us; speedup vs baseline: 1.1117x; 1.1117x over previous
//
#include <hip/hip_runtime.h>

// FISSA forward, MI355X. One workgroup per batch element (B=1024), 512 threads
// (8 waves). Register-blocked GEMMs: lane = output column (64), wave wv owns
// rows {wv+8r, r<7}. Each weight load feeds 7 FMAs; LayerNorms fused
// in-register (row/col ownership matches LN reduction layout).
// LDS: 4 x (50x66) fp32 + 50x51 fp32 + small = 64.8 KB.

#define NB 1024
#define LL 50
#define DD 64
#define LD 66   // even row stride (bank-group 2; broadcasts/stride-1 reads stay clean)
#define LDC 51
#define NR 7
#define NEGV (-4294967295.0f)

__device__ __forceinline__ float wsum(float v) {
#pragma unroll
  for (int m = 32; m >= 1; m >>= 1) v += __shfl_xor(v, m, 64);
  return v;
}
__device__ __forceinline__ float wmax(float v) {
#pragma unroll
  for (int m = 32; m >= 1; m >>= 1) v = fmaxf(v, __shfl_xor(v, m, 64));
  return v;
}
// in-register row LayerNorm (value per lane, 64 lanes = one row)
__device__ __forceinline__ float rowln(float v) {
  float m = wsum(v) * (1.f / 64.f);
  float df = v - m;
  float var = wsum(df * df) * (1.f / 64.f);
  return df / sqrtf(var + 1e-8f);
}

__global__ __launch_bounds__(512, 1) void fissa_kernel(
    const int* __restrict__ user_items, const int* __restrict__ pos_items,
    const int* __restrict__ neg_items, const float* __restrict__ pmask,
    const float* __restrict__ item_emb, const float* __restrict__ pos_emb,
    const float* __restrict__ Qs, const float* __restrict__ Ks,
    const float* __restrict__ Vs, const float* __restrict__ c1w,
    const float* __restrict__ c1b, const float* __restrict__ c2w,
    const float* __restrict__ c2b, const float* __restrict__ query,
    const float* __restrict__ Klba, const float* __restrict__ Vlba,
    const float* __restrict__ l1w, const float* __restrict__ l1b,
    const float* __restrict__ l2w, const float* __restrict__ l2b,
    const float* __restrict__ gw, const float* __restrict__ gb,
    float* __restrict__ out) {
  __shared__ float s_in[LL * LD];  // LN'd inputs (kept for LBA branch)
  __shared__ float s_x[LL * LD];   // current x / att / ff
  __shared__ float s_a[LL * LD];   // Qx -> Vx -> Kx_lba
  __shared__ float s_b[LL * LD];   // Kx -> h  -> Vx_lba
  __shared__ float s_c[LL * LDC];  // scores -> c1 -> c2
  __shared__ float s_mask[64], s_bias[64], s_qv[64], s_glo[64], s_gw[192], s_scal[2];

  const int b = blockIdx.x;
  const int tid = threadIdx.x;
  const int wv = tid >> 6, ln = tid & 63;

  // row set for this wave (clamped; store-guarded)
  int qrow[NR];   // clamped row index
  int qoff[NR];   // row*LD
  int coff[NR];   // row*LDC
  bool qok[NR];
#pragma unroll
  for (int r = 0; r < NR; ++r) {
    int q = wv + 8 * r;
    qok[r] = (q < LL);
    qrow[r] = qok[r] ? q : (LL - 1);
    qoff[r] = qrow[r] * LD;
    coff[r] = qrow[r] * LDC;
  }

  // ---- small params ----
  if (tid < 64) s_mask[tid] = (tid < LL) ? pmask[b * LL + tid] : 0.f;
  else if (tid < 128) s_qv[tid - 64] = query[tid - 64];
  else if (tid < 320) s_gw[tid - 128] = gw[tid - 128];

  // ---- gather + pos emb + mask + LN (fused in-register) ----
#pragma unroll
  for (int r = 0; r < NR; ++r) {
    int l = qrow[r];
    int u = user_items[b * LL + l];
    float mk = pmask[b * LL + l];
    float v = (item_emb[(size_t)u * DD + ln] + pos_emb[l * DD + ln]) * mk;
    float o = rowln(v);
    if (qok[r]) { s_in[qoff[r] + ln] = o; s_x[qoff[r] + ln] = o; }
  }
  __syncthreads();

  // ---- SAB layers ----
  for (int i = 0; i < 2; ++i) {
    const float* Qc = Qs + i * DD * DD + ln;
    const float* Kc = Ks + i * DD * DD + ln;
    const float* Vc = Vs + i * DD * DD + ln;

    // Qx -> s_a, Kx -> s_b (2 global + 7 broadcast LDS per 14 FMA)
    {
      float aq[NR], ak[NR];
#pragma unroll
      for (int r = 0; r < NR; ++r) { aq[r] = 0.f; ak[r] = 0.f; }
#pragma unroll 4
      for (int k = 0; k < DD; ++k) {
        float wq = Qc[k * DD];
        float wk = Kc[k * DD];
#pragma unroll
        for (int r = 0; r < NR; ++r) {
          float xv = s_x[qoff[r] + k];
          aq[r] = fmaf(xv, wq, aq[r]);
          ak[r] = fmaf(xv, wk, ak[r]);
        }
      }
#pragma unroll
      for (int r = 0; r < NR; ++r)
        if (qok[r]) { s_a[qoff[r] + ln] = aq[r]; s_b[qoff[r] + ln] = ak[r]; }
    }
    __syncthreads();

    // scores -> s_c (lane = k, raw masked scores, NO softmax)
    {
      float sc[NR];
#pragma unroll
      for (int r = 0; r < NR; ++r) sc[r] = 0.f;
      const int kk = (ln < LL) ? ln : (LL - 1);
      const float* krow = &s_b[kk * LD];
#pragma unroll 4
      for (int d = 0; d < DD; ++d) {
        float kv = krow[d];
#pragma unroll
        for (int r = 0; r < NR; ++r)
          sc[r] = fmaf(s_a[qoff[r] + d], kv, sc[r]);
      }
      if (ln < LL) {
        float mk = s_mask[ln];
#pragma unroll
        for (int r = 0; r < NR; ++r)
          if (qok[r]) {
            float v = sc[r] * 0.125f;       // / sqrt(64)
            if (ln > qrow[r]) v = NEGV;     // causal
            if (mk == 0.f) v = NEGV;        // key mask
            v *= s_mask[qrow[r]];           // * padding_mask[q]
            s_c[coff[r] + ln] = v;
          }
      }
    }
    __syncthreads();

    // Vx -> s_a (Qx dead)
    {
      float av[NR];
#pragma unroll
      for (int r = 0; r < NR; ++r) av[r] = 0.f;
#pragma unroll 4
      for (int k = 0; k < DD; ++k) {
        float wvv = Vc[k * DD];
#pragma unroll
        for (int r = 0; r < NR; ++r)
          av[r] = fmaf(s_x[qoff[r] + k], wvv, av[r]);
      }
#pragma unroll
      for (int r = 0; r < NR; ++r)
        if (qok[r]) s_a[qoff[r] + ln] = av[r];
    }
    __syncthreads();

    // att = scores@Vx + x, LN fused in-register -> s_x
    {
      float at[NR];
#pragma unroll
      for (int r = 0; r < NR; ++r) at[r] = s_x[qoff[r] + ln];  // residual (own elem)
#pragma unroll 2
      for (int k = 0; k < LL; ++k) {
        float vv = s_a[k * LD + ln];
#pragma unroll
        for (int r = 0; r < NR; ++r)
          at[r] = fmaf(s_c[coff[r] + k], vv, at[r]);
      }
#pragma unroll
      for (int r = 0; r < NR; ++r) {
        float o = rowln(at[r]);
        if (qok[r]) s_x[qoff[r] + ln] = o;
      }
    }
    __syncthreads();

    // stage c1 -> s_c, c1b -> s_bias
    for (int e = tid; e < LL * LL; e += 512) {
      int q = e / LL;
      s_c[q * LDC + (e - q * LL)] = c1w[i * LL * LL + e];
    }
    if (tid < LL) s_bias[tid] = c1b[i * LL + tid];
    __syncthreads();

    // h = relu(c1 @ att + c1b) -> s_b (Kx dead)
    {
      float hh[NR];
#pragma unroll
      for (int r = 0; r < NR; ++r) hh[r] = 0.f;
#pragma unroll 2
      for (int j = 0; j < LL; ++j) {
        float xv = s_x[j * LD + ln];
#pragma unroll
        for (int r = 0; r < NR; ++r)
          hh[r] = fmaf(s_c[coff[r] + j], xv, hh[r]);
      }
#pragma unroll
      for (int r = 0; r < NR; ++r)
        if (qok[r]) s_b[qoff[r] + ln] = fmaxf(hh[r] + s_bias[qrow[r]], 0.f);
    }
    __syncthreads();

    // stage c2 -> s_c, c2b -> s_bias
    for (int e = tid; e < LL * LL; e += 512) {
      int q = e / LL;
      s_c[q * LDC + (e - q * LL)] = c2w[i * LL * LL + e];
    }
    if (tid < LL) s_bias[tid] = c2b[i * LL + tid];
    __syncthreads();

    // ff = c2 @ h + c2b + att, *mask, LN fused -> s_x
    {
      float f0[NR];
#pragma unroll
      for (int r = 0; r < NR; ++r) f0[r] = s_x[qoff[r] + ln];  // att residual
#pragma unroll 2
      for (int j = 0; j < LL; ++j) {
        float hv = s_b[j * LD + ln];
#pragma unroll
        for (int r = 0; r < NR; ++r)
          f0[r] = fmaf(s_c[coff[r] + j], hv, f0[r]);
      }
#pragma unroll
      for (int r = 0; r < NR; ++r) {
        float v = (f0[r] + s_bias[qrow[r]]) * s_mask[qrow[r]];
        float o = rowln(v);
        if (qok[r]) s_x[qoff[r] + ln] = o;
      }
    }
    __syncthreads();
  }

  // ---- LBA branch: Kx -> s_a, Vx -> s_b from s_in ----
  {
    float akl[NR], avl[NR];
#pragma unroll
    for (int r = 0; r < NR; ++r) { akl[r] = 0.f; avl[r] = 0.f; }
    const float* Kc = Klba + ln;
    const float* Vc = Vlba + ln;
#pragma unroll 4
    for (int k = 0; k < DD; ++k) {
      float wk = Kc[k * DD];
      float wvv = Vc[k * DD];
#pragma unroll
      for (int r = 0; r < NR; ++r) {
        float xv = s_in[qoff[r] + k];
        akl[r] = fmaf(xv, wk, akl[r]);
        avl[r] = fmaf(xv, wvv, avl[r]);
      }
    }
#pragma unroll
    for (int r = 0; r < NR; ++r)
      if (qok[r]) { s_a[qoff[r] + ln] = akl[r]; s_b[qoff[r] + ln] = avl[r]; }
  }
  __syncthreads();

  if (wv == 0) {  // single-wave mini-stage (no barriers inside)
    float sc = -INFINITY;
    if (ln < LL) {
      float acc = 0.f;
#pragma unroll
      for (int d = 0; d < DD; ++d) acc += s_qv[d] * s_a[ln * LD + d];
      sc = acc;
      if (s_mask[ln] == 0.f) sc = NEGV;
    }
    float mx = wmax(sc);
    float e = (ln < LL) ? expf(sc - mx) : 0.f;
    float den = wsum(e);
    if (ln < LL) s_bias[ln] = e / den;  // softmax probs (same-wave DS ordering)
    float acc = 0.f;
#pragma unroll
    for (int l = 0; l < LL; ++l) acc += s_bias[l] * s_b[l * LD + ln];
    float g = rowln(acc);  // LN(glo)
    float w1 = l1w[0], bb1 = l1b[0], w2 = l2w[0], bb2 = l2b[0];
    float h = fmaxf(w1 * g + bb1, 0.f);
    float glo = rowln(w2 * h + bb2 + g);  // final glo
    s_glo[ln] = glo;
    float gs = wsum(glo * s_gw[64 + ln]);  // glo part of the gating logit
    if (ln == 0) s_scal[0] = gs + gb[0];
  }
  __syncthreads();

  // ---- gating + output: one wave per (pos/neg, l) row ----
  float g2c = s_scal[0];
  float gloc = s_glo[ln];
  for (int row = wv; row < 2 * LL; row += 8) {
    int sgn = row >= LL;
    int l = row - sgn * LL;
    int u = user_items[b * LL + l];
    int it = sgn ? neg_items[b * LL + l] : pos_items[b * LL + l];
    float ie_d = item_emb[(size_t)u * DD + ln];
    float mi_d = item_emb[(size_t)it * DD + ln];
    float logit = wsum(ie_d * s_gw[ln] + mi_d * s_gw[128 + ln]) + g2c;
    float sg = 1.f / (1.f + expf(-logit));
    float g = 1.f / (1.f + expf(-sg));  // sigmoid(sigmoid(logit))
    float od = (s_x[l * LD + ln] * g + gloc * (1.f - g)) * s_mask[l];
    float o = rowln(od);
    float res = wsum(o * mi_d);
    if (ln == 0) out[(sgn * NB + b) * LL + l] = res;
  }
}

extern "C" void kernel_launch(void* const* d_in, const int* in_sizes, int n_in,
                              void* d_out, int out_size, void* d_ws, size_t ws_size,
                              hipStream_t stream) {
  const int* user_items = (const int*)d_in[0];
  const int* pos_items = (const int*)d_in[1];
  const int* neg_items = (const int*)d_in[2];
  const float* pmask = (const float*)d_in[3];
  const float* item_emb = (const float*)d_in[4];
  const float* pos_emb = (const float*)d_in[5];
  const float* Qs = (const float*)d_in[6];
  const float* Ks = (const float*)d_in[7];
  const float* Vs = (const float*)d_in[8];
  const float* c1w = (const float*)d_in[9];
  const float* c1b = (const float*)d_in[10];
  const float* c2w = (const float*)d_in[11];
  const float* c2b = (const float*)d_in[12];
  const float* query = (const float*)d_in[13];
  const float* Klba = (const float*)d_in[14];
  const float* Vlba = (const float*)d_in[15];
  const float* l1w = (const float*)d_in[16];
  const float* l1b = (const float*)d_in[17];
  const float* l2w = (const float*)d_in[18];
  const float* l2b = (const float*)d_in[19];
  const float* gw = (const float*)d_in[20];
  const float* gb = (const float*)d_in[21];
  float* out = (float*)d_out;

  fissa_kernel<<<dim3(NB), dim3(512), 0, stream>>>(
      user_items, pos_items, neg_items, pmask, item_emb, pos_emb, Qs, Ks, Vs,
      c1w, c1b, c2w, c2b, query, Klba, Vlba, l1w, l1b, l2w, l2b, gw, gb, out);
}